// Round 1
// baseline (715.252 us; speedup 1.0000x reference)
//
#include <hip/hip_runtime.h>
#include <hip/hip_bf16.h>
#include <cstdint>
#include <cstddef>

// Problem constants
#define HIDDEN   768
#define HID_F    3072
#define PART     192
#define SHARED_F 576
#define NEXP     6
#define BATCH    32
#define SEQ      1024
#define M_TOK    (BATCH * SEQ)   // 32768

typedef __bf16 bf16;
typedef __attribute__((ext_vector_type(8))) __bf16 bf16x8;
typedef __attribute__((ext_vector_type(4))) __bf16 bf16x4;
typedef __attribute__((ext_vector_type(4))) float  f32x4;

// ---- async global -> LDS copy, 16B per lane -----------------------------
// HW semantics: LDS dest = wave-uniform base + lane*16; global addr per-lane.
__device__ __forceinline__ void gl2lds16(const void* g, void* l) {
    __builtin_amdgcn_global_load_lds(
        (const __attribute__((address_space(1))) void*)g,
        (__attribute__((address_space(3))) void*)l,
        16, 0, 0);
}

__device__ __forceinline__ float gelu_exact(float x) {
    return 0.5f * x * (1.0f + erff(x * 0.70710678118654752f));
}

// ---- prep: fp32 -> bf16 vectorized convert ------------------------------
__global__ __launch_bounds__(256) void cvt_f32_bf16(
        const float4* __restrict__ src, bf16x4* __restrict__ dst, int n4) {
    int i      = blockIdx.x * 256 + threadIdx.x;
    int stride = gridDim.x * 256;
    for (; i < n4; i += stride) {
        float4 v = src[i];
        bf16x4 o = { (__bf16)v.x, (__bf16)v.y, (__bf16)v.z, (__bf16)v.w };
        dst[i] = o;
    }
}

// ---- prep: tiled transpose fp32[K][N] -> bf16[N][K] ---------------------
__global__ __launch_bounds__(256) void transpose_cvt(
        const float* __restrict__ src, bf16* __restrict__ dst, int K, int N) {
    __shared__ float t[32][33];
    const int n0 = blockIdx.x * 32, k0 = blockIdx.y * 32;
    const int tx = threadIdx.x & 31, ty = threadIdx.x >> 5;  // ty in 0..7
#pragma unroll
    for (int p = 0; p < 4; ++p) {
        int r = ty + p * 8;
        t[r][tx] = src[(size_t)(k0 + r) * N + n0 + tx];
    }
    __syncthreads();
#pragma unroll
    for (int p = 0; p < 4; ++p) {
        int rn = ty + p * 8;
        dst[(size_t)(n0 + rn) * K + k0 + tx] = (bf16)t[tx][rn];
    }
}

// ---- prep: Wcat[e][n][k] = (n<576 ? W2[k][n] : We[e][k][n-576]) as bf16 --
__global__ __launch_bounds__(256) void build_wcat(
        const float* __restrict__ W2, const float* __restrict__ We,
        bf16* __restrict__ Wcat) {
    __shared__ float t[32][33];
    const int e  = blockIdx.z;
    const int n0 = blockIdx.x * 32;   // output row tile (col of original)
    const int k0 = blockIdx.y * 32;   // k tile
    const int tx = threadIdx.x & 31, ty = threadIdx.x >> 5;
    const float* src;
    int ld, c;
    if (n0 < SHARED_F) { src = W2; ld = SHARED_F; c = n0 + tx; }
    else { src = We + (size_t)e * HID_F * PART; ld = PART; c = n0 + tx - SHARED_F; }
#pragma unroll
    for (int p = 0; p < 4; ++p) {
        int r = ty + p * 8;
        t[r][tx] = src[(size_t)(k0 + r) * ld + c];
    }
    __syncthreads();
    bf16* dst = Wcat + (size_t)e * HIDDEN * HID_F;
#pragma unroll
    for (int p = 0; p < 4; ++p) {
        int rn = ty + p * 8;
        dst[(size_t)(n0 + rn) * HID_F + k0 + tx] = (bf16)t[tx][rn];
    }
}

// ---- GEMM 1: h = gelu(hb @ W1t^T + b1), bf16 out ------------------------
// C[m][n] = sum_k A[m][k]*Bt[n][k]; tiles 128x128xBK32, 4 waves (2x2 of 64x64)
__global__ __launch_bounds__(256) void fc1_gelu(
        const bf16* __restrict__ A,   // [32768][768]
        const bf16* __restrict__ Bt,  // [3072][768]
        const float* __restrict__ b1, // [3072]
        bf16* __restrict__ H) {       // [32768][3072]
    __shared__ alignas(16) bf16 As[128 * 32];
    __shared__ alignas(16) bf16 Bs[128 * 32];
    const int tid  = threadIdx.x;
    const int wave = tid >> 6, lane = tid & 63;
    const int wm = wave >> 1, wn = wave & 1;
    const int lrow = lane & 15, lk8 = lane >> 4;
    const int m0 = blockIdx.y * 128;
    const int n0 = blockIdx.x * 128;
    const int srow = lane >> 2;            // 0..15
    const int schunk = (lane & 3) * 8;     // 0,8,16,24 elements

    f32x4 acc[4][4] = {};
    for (int k0 = 0; k0 < HIDDEN; k0 += 32) {
#pragma unroll
        for (int i = 0; i < 2; ++i) {
            int r0 = wave * 32 + i * 16;
            gl2lds16(A  + (size_t)(m0 + r0 + srow) * HIDDEN + k0 + schunk, As + r0 * 32);
            gl2lds16(Bt + (size_t)(n0 + r0 + srow) * HIDDEN + k0 + schunk, Bs + r0 * 32);
        }
        __syncthreads();   // drains vmcnt -> LDS visible
        bf16x8 af[4], bfr[4];
#pragma unroll
        for (int mi = 0; mi < 4; ++mi)
            af[mi] = *(const bf16x8*)(As + (wm * 64 + mi * 16 + lrow) * 32 + lk8 * 8);
#pragma unroll
        for (int ni = 0; ni < 4; ++ni)
            bfr[ni] = *(const bf16x8*)(Bs + (wn * 64 + ni * 16 + lrow) * 32 + lk8 * 8);
#pragma unroll
        for (int mi = 0; mi < 4; ++mi)
#pragma unroll
            for (int ni = 0; ni < 4; ++ni)
                acc[mi][ni] = __builtin_amdgcn_mfma_f32_16x16x32_bf16(
                    af[mi], bfr[ni], acc[mi][ni], 0, 0, 0);
        __syncthreads();   // protect LDS before next stage
    }
#pragma unroll
    for (int mi = 0; mi < 4; ++mi) {
#pragma unroll
        for (int ni = 0; ni < 4; ++ni) {
            int col = n0 + wn * 64 + ni * 16 + lrow;
            float bias = b1[col];
#pragma unroll
            for (int r = 0; r < 4; ++r) {
                int row = m0 + wm * 64 + mi * 16 + lk8 * 4 + r;
                float v = acc[mi][ni][r] + bias;
                H[(size_t)row * HID_F + col] = (bf16)gelu_exact(v);
            }
        }
    }
}

// ---- GEMM 2: out = h @ Wcat[idx[b]]^T + bias_cat, fp32 out --------------
__global__ __launch_bounds__(256) void fc2_moe(
        const bf16* __restrict__ H,     // [32768][3072]
        const bf16* __restrict__ Wcat,  // [6][768][3072]
        const float* __restrict__ b2,   // [576]
        const float* __restrict__ be,   // [6][192]
        const int*  __restrict__ idx,   // [32]
        float* __restrict__ Out) {      // [32768][768]
    __shared__ alignas(16) bf16 As[128 * 32];
    __shared__ alignas(16) bf16 Bs[128 * 32];
    const int tid  = threadIdx.x;
    const int wave = tid >> 6, lane = tid & 63;
    const int wm = wave >> 1, wn = wave & 1;
    const int lrow = lane & 15, lk8 = lane >> 4;
    const int mt = blockIdx.y;
    const int m0 = mt * 128;
    const int n0 = blockIdx.x * 128;
    int e = idx[mt >> 3];                       // 8 m-tiles per batch elem
    e = e < 0 ? 0 : (e > NEXP - 1 ? NEXP - 1 : e);
    const bf16* Bt = Wcat + (size_t)e * HIDDEN * HID_F;
    const int srow = lane >> 2;
    const int schunk = (lane & 3) * 8;

    f32x4 acc[4][4] = {};
    for (int k0 = 0; k0 < HID_F; k0 += 32) {
#pragma unroll
        for (int i = 0; i < 2; ++i) {
            int r0 = wave * 32 + i * 16;
            gl2lds16(H  + (size_t)(m0 + r0 + srow) * HID_F + k0 + schunk, As + r0 * 32);
            gl2lds16(Bt + (size_t)(n0 + r0 + srow) * HID_F + k0 + schunk, Bs + r0 * 32);
        }
        __syncthreads();
        bf16x8 af[4], bfr[4];
#pragma unroll
        for (int mi = 0; mi < 4; ++mi)
            af[mi] = *(const bf16x8*)(As + (wm * 64 + mi * 16 + lrow) * 32 + lk8 * 8);
#pragma unroll
        for (int ni = 0; ni < 4; ++ni)
            bfr[ni] = *(const bf16x8*)(Bs + (wn * 64 + ni * 16 + lrow) * 32 + lk8 * 8);
#pragma unroll
        for (int mi = 0; mi < 4; ++mi)
#pragma unroll
            for (int ni = 0; ni < 4; ++ni)
                acc[mi][ni] = __builtin_amdgcn_mfma_f32_16x16x32_bf16(
                    af[mi], bfr[ni], acc[mi][ni], 0, 0, 0);
        __syncthreads();
    }
#pragma unroll
    for (int mi = 0; mi < 4; ++mi) {
#pragma unroll
        for (int ni = 0; ni < 4; ++ni) {
            int col = n0 + wn * 64 + ni * 16 + lrow;
            float bias = (col < SHARED_F) ? b2[col] : be[e * PART + col - SHARED_F];
#pragma unroll
            for (int r = 0; r < 4; ++r) {
                int row = m0 + wm * 64 + mi * 16 + lk8 * 4 + r;
                Out[(size_t)row * HIDDEN + col] = acc[mi][ni][r] + bias;
            }
        }
    }
}

extern "C" void kernel_launch(void* const* d_in, const int* in_sizes, int n_in,
                              void* d_out, int out_size, void* d_ws, size_t ws_size,
                              hipStream_t stream) {
    const float* hidden = (const float*)d_in[0];
    const int*   idx    = (const int*)d_in[1];   // see risk note: ref dtype int64
    const float* W1     = (const float*)d_in[2];
    const float* b1     = (const float*)d_in[3];
    const float* W2     = (const float*)d_in[4];
    const float* b2     = (const float*)d_in[5];
    const float* We     = (const float*)d_in[6];
    const float* be     = (const float*)d_in[7];
    float* out = (float*)d_out;

    // workspace layout (bytes)
    char* ws = (char*)d_ws;
    bf16* hb   = (bf16*)(ws);                       //  50,331,648 B: [32768][768]
    bf16* h    = (bf16*)(ws + 50331648);            // 201,326,592 B: [32768][3072]
    bf16* W1t  = (bf16*)(ws + 251658240);           //   4,718,592 B: [3072][768]
    bf16* Wcat = (bf16*)(ws + 256376832);           //  28,311,552 B: [6][768][3072]
    // total 284,688,384 B

    // prep
    cvt_f32_bf16<<<4096, 256, 0, stream>>>(
        (const float4*)hidden, (bf16x4*)hb, (M_TOK * HIDDEN) / 4);
    transpose_cvt<<<dim3(HID_F / 32, HIDDEN / 32), 256, 0, stream>>>(
        W1, W1t, HIDDEN, HID_F);
    build_wcat<<<dim3(HIDDEN / 32, HID_F / 32, NEXP), 256, 0, stream>>>(
        W2, We, Wcat);

    // GEMM 1: [32768,768] x [768,3072] -> h (bf16, gelu fused)
    fc1_gelu<<<dim3(HID_F / 128, M_TOK / 128), 256, 0, stream>>>(hb, W1t, b1, h);

    // GEMM 2: per-batch [1024,3072] x [3072,768] -> out (fp32, bias fused)
    fc2_moe<<<dim3(HIDDEN / 128, M_TOK / 128), 256, 0, stream>>>(
        h, Wcat, b2, be, idx, out);
}

// Round 2
// 668.628 us; speedup vs baseline: 1.0697x; 1.0697x over previous
//
#include <hip/hip_runtime.h>
#include <hip/hip_bf16.h>
#include <cstdint>
#include <cstddef>

// Problem constants
#define HIDDEN   768
#define HID_F    3072
#define PART     192
#define SHARED_F 576
#define NEXP     6
#define BATCH    32
#define SEQ      1024
#define M_TOK    (BATCH * SEQ)   // 32768

typedef __bf16 bf16;
typedef __attribute__((ext_vector_type(8))) __bf16 bf16x8;
typedef __attribute__((ext_vector_type(4))) __bf16 bf16x4;
typedef __attribute__((ext_vector_type(4))) float  f32x4;

// ---- async global -> LDS copy, 16B per lane -----------------------------
// HW semantics: LDS dest = wave-uniform base + lane*16; global addr per-lane.
__device__ __forceinline__ void gl2lds16(const void* g, void* l) {
    __builtin_amdgcn_global_load_lds(
        (const __attribute__((address_space(1))) void*)g,
        (__attribute__((address_space(3))) void*)l,
        16, 0, 0);
}

// Exact-GELU via Abramowitz-Stegun 7.1.26 rational erf (|eps| <= 1.5e-7).
// ~14 VALU ops (1 v_exp, 1 v_rcp) vs libm erff's ~30+.
__device__ __forceinline__ float gelu_fast(float x) {
    float xs = x * 0.70710678118654752f;       // x / sqrt(2)
    float ax = __builtin_fabsf(xs);
    float t  = __builtin_amdgcn_rcpf(1.0f + 0.3275911f * ax);
    float p  = t * (0.254829592f +
               t * (-0.284496736f +
               t * (1.421413741f +
               t * (-1.453152027f +
               t * 1.061405429f))));
    float e  = __expf(-xs * xs);
    float er = 1.0f - p * e;                   // erf(|xs|)
    er = (xs < 0.0f) ? -er : er;
    return 0.5f * x * (1.0f + er);
}

// ---- prep: fp32 -> bf16 vectorized convert ------------------------------
__global__ __launch_bounds__(256) void cvt_f32_bf16(
        const float4* __restrict__ src, bf16x4* __restrict__ dst, int n4) {
    int i      = blockIdx.x * 256 + threadIdx.x;
    int stride = gridDim.x * 256;
    for (; i < n4; i += stride) {
        float4 v = src[i];
        bf16x4 o = { (__bf16)v.x, (__bf16)v.y, (__bf16)v.z, (__bf16)v.w };
        dst[i] = o;
    }
}

// ---- prep: tiled transpose fp32[K][N] -> bf16[N][K] ---------------------
__global__ __launch_bounds__(256) void transpose_cvt(
        const float* __restrict__ src, bf16* __restrict__ dst, int K, int N) {
    __shared__ float t[32][33];
    const int n0 = blockIdx.x * 32, k0 = blockIdx.y * 32;
    const int tx = threadIdx.x & 31, ty = threadIdx.x >> 5;  // ty in 0..7
#pragma unroll
    for (int p = 0; p < 4; ++p) {
        int r = ty + p * 8;
        t[r][tx] = src[(size_t)(k0 + r) * N + n0 + tx];
    }
    __syncthreads();
#pragma unroll
    for (int p = 0; p < 4; ++p) {
        int rn = ty + p * 8;
        dst[(size_t)(n0 + rn) * K + k0 + tx] = (bf16)t[tx][rn];
    }
}

// ---- prep: Wcat[e][n][k] = (n<576 ? W2[k][n] : We[e][k][n-576]) as bf16 --
__global__ __launch_bounds__(256) void build_wcat(
        const float* __restrict__ W2, const float* __restrict__ We,
        bf16* __restrict__ Wcat) {
    __shared__ float t[32][33];
    const int e  = blockIdx.z;
    const int n0 = blockIdx.x * 32;   // output row tile (col of original)
    const int k0 = blockIdx.y * 32;   // k tile
    const int tx = threadIdx.x & 31, ty = threadIdx.x >> 5;
    const float* src;
    int ld, c;
    if (n0 < SHARED_F) { src = W2; ld = SHARED_F; c = n0 + tx; }
    else { src = We + (size_t)e * HID_F * PART; ld = PART; c = n0 + tx - SHARED_F; }
#pragma unroll
    for (int p = 0; p < 4; ++p) {
        int r = ty + p * 8;
        t[r][tx] = src[(size_t)(k0 + r) * ld + c];
    }
    __syncthreads();
    bf16* dst = Wcat + (size_t)e * HIDDEN * HID_F;
#pragma unroll
    for (int p = 0; p < 4; ++p) {
        int rn = ty + p * 8;
        dst[(size_t)(n0 + rn) * HID_F + k0 + tx] = (bf16)t[tx][rn];
    }
}

// LDS tile layout (both GEMMs): row-major [128][32] bf16, 64 B/row, with the
// four 16 B chunks of each row XOR-swizzled: phys_chunk = c ^ ((row>>1)&3).
// Staging side implements this by permuting the GLOBAL source chunk per lane
// (global_load_lds dest is fixed base+lane*16); frag reads XOR-correct.
// Result: quarter-wave frag-read phases hit 8 distinct bank groups, residual
// 2-way aliasing only (free per m136).

// ---- GEMM 1: h = gelu(hb @ W1t^T + b1), bf16 out ------------------------
__global__ __launch_bounds__(256) void fc1_gelu(
        const bf16* __restrict__ A,   // [32768][768]
        const bf16* __restrict__ Bt,  // [3072][768]
        const float* __restrict__ b1, // [3072]
        bf16* __restrict__ H) {       // [32768][3072]
    __shared__ alignas(16) bf16 As[128 * 32];
    __shared__ alignas(16) bf16 Bs[128 * 32];
    const int tid  = threadIdx.x;
    const int wave = tid >> 6, lane = tid & 63;
    const int wm = wave >> 1, wn = wave & 1;
    const int lrow = lane & 15, lk8 = lane >> 4;
    const int m0 = blockIdx.y * 128;
    const int n0 = blockIdx.x * 128;
    // staging: lane -> (row = lane>>2, phys chunk = lane&3); fetch swizzled
    // global chunk so that logical chunk c lands at phys c ^ ((row>>1)&3)
    const int srow   = lane >> 2;
    const int schunk = (((lane & 3) ^ ((lane >> 3) & 3))) * 8;  // elements
    // frag read: logical chunk lk8 lives at phys chunk lk8 ^ ((lrow>>1)&3)
    const int rchunk = ((lk8 ^ ((lrow >> 1) & 3))) * 8;         // elements

    const bf16* gA0 = A  + (size_t)(m0 + wave * 32 + srow) * HIDDEN + schunk;
    const bf16* gA1 = gA0 + 16 * HIDDEN;
    const bf16* gB0 = Bt + (size_t)(n0 + wave * 32 + srow) * HIDDEN + schunk;
    const bf16* gB1 = gB0 + 16 * HIDDEN;
    bf16* lA0 = As + (wave * 32) * 32;
    bf16* lA1 = lA0 + 16 * 32;
    bf16* lB0 = Bs + (wave * 32) * 32;
    bf16* lB1 = lB0 + 16 * 32;

    f32x4 acc[4][4] = {};
    for (int k0 = 0; k0 < HIDDEN; k0 += 32) {
        gl2lds16(gA0, lA0); gl2lds16(gA1, lA1);
        gl2lds16(gB0, lB0); gl2lds16(gB1, lB1);
        gA0 += 32; gA1 += 32; gB0 += 32; gB1 += 32;
        __syncthreads();   // drains vmcnt -> LDS visible
        bf16x8 af[4], bfr[4];
#pragma unroll
        for (int mi = 0; mi < 4; ++mi)
            af[mi] = *(const bf16x8*)(As + (wm * 64 + mi * 16 + lrow) * 32 + rchunk);
#pragma unroll
        for (int ni = 0; ni < 4; ++ni)
            bfr[ni] = *(const bf16x8*)(Bs + (wn * 64 + ni * 16 + lrow) * 32 + rchunk);
#pragma unroll
        for (int mi = 0; mi < 4; ++mi)
#pragma unroll
            for (int ni = 0; ni < 4; ++ni)
                acc[mi][ni] = __builtin_amdgcn_mfma_f32_16x16x32_bf16(
                    af[mi], bfr[ni], acc[mi][ni], 0, 0, 0);
        __syncthreads();   // protect LDS before next stage
    }
#pragma unroll
    for (int mi = 0; mi < 4; ++mi) {
#pragma unroll
        for (int ni = 0; ni < 4; ++ni) {
            int col = n0 + wn * 64 + ni * 16 + lrow;
            float bias = b1[col];
#pragma unroll
            for (int r = 0; r < 4; ++r) {
                int row = m0 + wm * 64 + mi * 16 + lk8 * 4 + r;
                float v = acc[mi][ni][r] + bias;
                H[(size_t)row * HID_F + col] = (bf16)gelu_fast(v);
            }
        }
    }
}

// ---- GEMM 2: out = h @ Wcat[idx[b]]^T + bias_cat, fp32 out --------------
__global__ __launch_bounds__(256) void fc2_moe(
        const bf16* __restrict__ H,     // [32768][3072]
        const bf16* __restrict__ Wcat,  // [6][768][3072]
        const float* __restrict__ b2,   // [576]
        const float* __restrict__ be,   // [6][192]
        const int*  __restrict__ idx,   // [32]
        float* __restrict__ Out) {      // [32768][768]
    __shared__ alignas(16) bf16 As[128 * 32];
    __shared__ alignas(16) bf16 Bs[128 * 32];
    const int tid  = threadIdx.x;
    const int wave = tid >> 6, lane = tid & 63;
    const int wm = wave >> 1, wn = wave & 1;
    const int lrow = lane & 15, lk8 = lane >> 4;
    const int mt = blockIdx.y;
    const int m0 = mt * 128;
    const int n0 = blockIdx.x * 128;
    int e = idx[mt >> 3];                       // 8 m-tiles per batch elem
    e = e < 0 ? 0 : (e > NEXP - 1 ? NEXP - 1 : e);
    const bf16* Bt = Wcat + (size_t)e * HIDDEN * HID_F;
    const int srow   = lane >> 2;
    const int schunk = (((lane & 3) ^ ((lane >> 3) & 3))) * 8;
    const int rchunk = ((lk8 ^ ((lrow >> 1) & 3))) * 8;

    const bf16* gA0 = H  + (size_t)(m0 + wave * 32 + srow) * HID_F + schunk;
    const bf16* gA1 = gA0 + 16 * HID_F;
    const bf16* gB0 = Bt + (size_t)(n0 + wave * 32 + srow) * HID_F + schunk;
    const bf16* gB1 = gB0 + 16 * HID_F;
    bf16* lA0 = As + (wave * 32) * 32;
    bf16* lA1 = lA0 + 16 * 32;
    bf16* lB0 = Bs + (wave * 32) * 32;
    bf16* lB1 = lB0 + 16 * 32;

    f32x4 acc[4][4] = {};
    for (int k0 = 0; k0 < HID_F; k0 += 32) {
        gl2lds16(gA0, lA0); gl2lds16(gA1, lA1);
        gl2lds16(gB0, lB0); gl2lds16(gB1, lB1);
        gA0 += 32; gA1 += 32; gB0 += 32; gB1 += 32;
        __syncthreads();
        bf16x8 af[4], bfr[4];
#pragma unroll
        for (int mi = 0; mi < 4; ++mi)
            af[mi] = *(const bf16x8*)(As + (wm * 64 + mi * 16 + lrow) * 32 + rchunk);
#pragma unroll
        for (int ni = 0; ni < 4; ++ni)
            bfr[ni] = *(const bf16x8*)(Bs + (wn * 64 + ni * 16 + lrow) * 32 + rchunk);
#pragma unroll
        for (int mi = 0; mi < 4; ++mi)
#pragma unroll
            for (int ni = 0; ni < 4; ++ni)
                acc[mi][ni] = __builtin_amdgcn_mfma_f32_16x16x32_bf16(
                    af[mi], bfr[ni], acc[mi][ni], 0, 0, 0);
        __syncthreads();
    }
#pragma unroll
    for (int mi = 0; mi < 4; ++mi) {
#pragma unroll
        for (int ni = 0; ni < 4; ++ni) {
            int col = n0 + wn * 64 + ni * 16 + lrow;
            float bias = (col < SHARED_F) ? b2[col] : be[e * PART + col - SHARED_F];
#pragma unroll
            for (int r = 0; r < 4; ++r) {
                int row = m0 + wm * 64 + mi * 16 + lk8 * 4 + r;
                Out[(size_t)row * HIDDEN + col] = acc[mi][ni][r] + bias;
            }
        }
    }
}

extern "C" void kernel_launch(void* const* d_in, const int* in_sizes, int n_in,
                              void* d_out, int out_size, void* d_ws, size_t ws_size,
                              hipStream_t stream) {
    const float* hidden = (const float*)d_in[0];
    const int*   idx    = (const int*)d_in[1];
    const float* W1     = (const float*)d_in[2];
    const float* b1     = (const float*)d_in[3];
    const float* W2     = (const float*)d_in[4];
    const float* b2     = (const float*)d_in[5];
    const float* We     = (const float*)d_in[6];
    const float* be     = (const float*)d_in[7];
    float* out = (float*)d_out;

    // workspace layout (bytes)
    char* ws = (char*)d_ws;
    bf16* hb   = (bf16*)(ws);                       //  50,331,648 B: [32768][768]
    bf16* h    = (bf16*)(ws + 50331648);            // 201,326,592 B: [32768][3072]
    bf16* W1t  = (bf16*)(ws + 251658240);           //   4,718,592 B: [3072][768]
    bf16* Wcat = (bf16*)(ws + 256376832);           //  28,311,552 B: [6][768][3072]
    // total 284,688,384 B

    // prep
    cvt_f32_bf16<<<4096, 256, 0, stream>>>(
        (const float4*)hidden, (bf16x4*)hb, (M_TOK * HIDDEN) / 4);
    transpose_cvt<<<dim3(HID_F / 32, HIDDEN / 32), 256, 0, stream>>>(
        W1, W1t, HIDDEN, HID_F);
    build_wcat<<<dim3(HIDDEN / 32, HID_F / 32, NEXP), 256, 0, stream>>>(
        W2, We, Wcat);

    // GEMM 1: [32768,768] x [768,3072] -> h (bf16, gelu fused)
    fc1_gelu<<<dim3(HID_F / 128, M_TOK / 128), 256, 0, stream>>>(hb, W1t, b1, h);

    // GEMM 2: per-batch [1024,3072] x [3072,768] -> out (fp32, bias fused)
    fc2_moe<<<dim3(HIDDEN / 128, M_TOK / 128), 256, 0, stream>>>(
        h, Wcat, b2, be, idx, out);
}

// Round 3
// 617.983 us; speedup vs baseline: 1.1574x; 1.0820x over previous
//
#include <hip/hip_runtime.h>
#include <hip/hip_bf16.h>
#include <cstdint>
#include <cstddef>

// Problem constants
#define HIDDEN   768
#define HID_F    3072
#define PART     192
#define SHARED_F 576
#define NEXP     6
#define BATCH    32
#define SEQ      1024
#define M_TOK    (BATCH * SEQ)   // 32768

typedef __bf16 bf16;
typedef __attribute__((ext_vector_type(8))) __bf16 bf16x8;
typedef __attribute__((ext_vector_type(4))) __bf16 bf16x4;
typedef __attribute__((ext_vector_type(4))) float  f32x4;

// ---- async global -> LDS copy, 16B per lane -----------------------------
__device__ __forceinline__ void gl2lds16(const void* g, void* l) {
    __builtin_amdgcn_global_load_lds(
        (const __attribute__((address_space(1))) void*)g,
        (__attribute__((address_space(3))) void*)l,
        16, 0, 0);
}

// Exact-GELU via Abramowitz-Stegun 7.1.26 rational erf (|eps| <= 1.5e-7).
__device__ __forceinline__ float gelu_fast(float x) {
    float xs = x * 0.70710678118654752f;       // x / sqrt(2)
    float ax = __builtin_fabsf(xs);
    float t  = __builtin_amdgcn_rcpf(1.0f + 0.3275911f * ax);
    float p  = t * (0.254829592f +
               t * (-0.284496736f +
               t * (1.421413741f +
               t * (-1.453152027f +
               t * 1.061405429f))));
    float e  = __expf(-xs * xs);
    float er = 1.0f - p * e;                   // erf(|xs|)
    er = (xs < 0.0f) ? -er : er;
    return 0.5f * x * (1.0f + er);
}

// ---- prep: fp32 -> bf16 vectorized convert ------------------------------
__global__ __launch_bounds__(256) void cvt_f32_bf16(
        const float4* __restrict__ src, bf16x4* __restrict__ dst, int n4) {
    int i      = blockIdx.x * 256 + threadIdx.x;
    int stride = gridDim.x * 256;
    for (; i < n4; i += stride) {
        float4 v = src[i];
        bf16x4 o = { (__bf16)v.x, (__bf16)v.y, (__bf16)v.z, (__bf16)v.w };
        dst[i] = o;
    }
}

// ---- prep: tiled transpose fp32[K][N] -> bf16[N][K] ---------------------
__global__ __launch_bounds__(256) void transpose_cvt(
        const float* __restrict__ src, bf16* __restrict__ dst, int K, int N) {
    __shared__ float t[32][33];
    const int n0 = blockIdx.x * 32, k0 = blockIdx.y * 32;
    const int tx = threadIdx.x & 31, ty = threadIdx.x >> 5;  // ty in 0..7
#pragma unroll
    for (int p = 0; p < 4; ++p) {
        int r = ty + p * 8;
        t[r][tx] = src[(size_t)(k0 + r) * N + n0 + tx];
    }
    __syncthreads();
#pragma unroll
    for (int p = 0; p < 4; ++p) {
        int rn = ty + p * 8;
        dst[(size_t)(n0 + rn) * K + k0 + tx] = (bf16)t[tx][rn];
    }
}

// ---- prep: Wcat[e][n][k] = (n<576 ? W2[k][n] : We[e][k][n-576]) as bf16 --
__global__ __launch_bounds__(256) void build_wcat(
        const float* __restrict__ W2, const float* __restrict__ We,
        bf16* __restrict__ Wcat) {
    __shared__ float t[32][33];
    const int e  = blockIdx.z;
    const int n0 = blockIdx.x * 32;   // output row tile (col of original)
    const int k0 = blockIdx.y * 32;   // k tile
    const int tx = threadIdx.x & 31, ty = threadIdx.x >> 5;
    const float* src;
    int ld, c;
    if (n0 < SHARED_F) { src = W2; ld = SHARED_F; c = n0 + tx; }
    else { src = We + (size_t)e * HID_F * PART; ld = PART; c = n0 + tx - SHARED_F; }
#pragma unroll
    for (int p = 0; p < 4; ++p) {
        int r = ty + p * 8;
        t[r][tx] = src[(size_t)(k0 + r) * ld + c];
    }
    __syncthreads();
    bf16* dst = Wcat + (size_t)e * HIDDEN * HID_F;
#pragma unroll
    for (int p = 0; p < 4; ++p) {
        int rn = ty + p * 8;
        dst[(size_t)(n0 + rn) * HID_F + k0 + tx] = (bf16)t[tx][rn];
    }
}

// LDS tile layout (both GEMMs): row-major [128][32] bf16, 64 B/row, chunks
// XOR-swizzled (phys_chunk = c ^ ((row>>1)&3)) -> 0 bank conflicts (R2 PMC).
//
// XCD swizzle (R3): 1D grid; xcd = L&7, j = L>>3; mt = xcd*32 + j/NT,
// nt = j%NT. All n-tiles of one m-tile land on ONE XCD -> A-slab fetched
// into exactly one L2 (was 6-8x overfetch, FETCH_SIZE 812 MB in fc2).

// ---- GEMM 1: h = gelu(hb @ W1t^T + b1), bf16 out ------------------------
__global__ __launch_bounds__(256) void fc1_gelu(
        const bf16* __restrict__ A,   // [32768][768]
        const bf16* __restrict__ Bt,  // [3072][768]
        const float* __restrict__ b1, // [3072]
        bf16* __restrict__ H) {       // [32768][3072]
    __shared__ alignas(16) bf16 As[128 * 32];
    __shared__ alignas(16) bf16 Bs[128 * 32];
    const int tid  = threadIdx.x;
    const int wave = tid >> 6, lane = tid & 63;
    const int wm = wave >> 1, wn = wave & 1;
    const int lrow = lane & 15, lk8 = lane >> 4;

    // XCD-gather swizzle: NT = 24 n-tiles, 256 m-tiles, 8 XCDs -> 32 mt/xcd
    const int L   = blockIdx.x;        // 0..6143
    const int xcd = L & 7;
    const int j   = L >> 3;            // 0..767
    const int jm  = j / 24;
    const int mt  = xcd * 32 + jm;
    const int nt  = j - jm * 24;
    const int m0 = mt * 128;
    const int n0 = nt * 128;

    const int srow   = lane >> 2;
    const int schunk = (((lane & 3) ^ ((lane >> 3) & 3))) * 8;  // elements
    const int rchunk = ((lk8 ^ ((lrow >> 1) & 3))) * 8;         // elements

    const bf16* gA0 = A  + (size_t)(m0 + wave * 32 + srow) * HIDDEN + schunk;
    const bf16* gA1 = gA0 + 16 * HIDDEN;
    const bf16* gB0 = Bt + (size_t)(n0 + wave * 32 + srow) * HIDDEN + schunk;
    const bf16* gB1 = gB0 + 16 * HIDDEN;
    bf16* lA0 = As + (wave * 32) * 32;
    bf16* lA1 = lA0 + 16 * 32;
    bf16* lB0 = Bs + (wave * 32) * 32;
    bf16* lB1 = lB0 + 16 * 32;

    f32x4 acc[4][4] = {};
    for (int k0 = 0; k0 < HIDDEN; k0 += 32) {
        gl2lds16(gA0, lA0); gl2lds16(gA1, lA1);
        gl2lds16(gB0, lB0); gl2lds16(gB1, lB1);
        gA0 += 32; gA1 += 32; gB0 += 32; gB1 += 32;
        __syncthreads();   // drains vmcnt -> LDS visible
        bf16x8 af[4], bfr[4];
#pragma unroll
        for (int mi = 0; mi < 4; ++mi)
            af[mi] = *(const bf16x8*)(As + (wm * 64 + mi * 16 + lrow) * 32 + rchunk);
#pragma unroll
        for (int ni = 0; ni < 4; ++ni)
            bfr[ni] = *(const bf16x8*)(Bs + (wn * 64 + ni * 16 + lrow) * 32 + rchunk);
#pragma unroll
        for (int mi = 0; mi < 4; ++mi)
#pragma unroll
            for (int ni = 0; ni < 4; ++ni)
                acc[mi][ni] = __builtin_amdgcn_mfma_f32_16x16x32_bf16(
                    af[mi], bfr[ni], acc[mi][ni], 0, 0, 0);
        __syncthreads();   // protect LDS before next stage
    }
#pragma unroll
    for (int mi = 0; mi < 4; ++mi) {
#pragma unroll
        for (int ni = 0; ni < 4; ++ni) {
            int col = n0 + wn * 64 + ni * 16 + lrow;
            float bias = b1[col];
#pragma unroll
            for (int r = 0; r < 4; ++r) {
                int row = m0 + wm * 64 + mi * 16 + lk8 * 4 + r;
                float v = acc[mi][ni][r] + bias;
                H[(size_t)row * HID_F + col] = (bf16)gelu_fast(v);
            }
        }
    }
}

// ---- GEMM 2: out = h @ Wcat[idx[b]]^T + bias_cat, fp32 out --------------
__global__ __launch_bounds__(256) void fc2_moe(
        const bf16* __restrict__ H,     // [32768][3072]
        const bf16* __restrict__ Wcat,  // [6][768][3072]
        const float* __restrict__ b2,   // [576]
        const float* __restrict__ be,   // [6][192]
        const int*  __restrict__ idx,   // [32]
        float* __restrict__ Out) {      // [32768][768]
    __shared__ alignas(16) bf16 As[128 * 32];
    __shared__ alignas(16) bf16 Bs[128 * 32];
    const int tid  = threadIdx.x;
    const int wave = tid >> 6, lane = tid & 63;
    const int wm = wave >> 1, wn = wave & 1;
    const int lrow = lane & 15, lk8 = lane >> 4;

    // XCD-gather swizzle: NT = 6 n-tiles, 256 m-tiles, 8 XCDs -> 32 mt/xcd
    const int L   = blockIdx.x;        // 0..1535
    const int xcd = L & 7;
    const int j   = L >> 3;            // 0..191
    const int jm  = j / 6;
    const int mt  = xcd * 32 + jm;
    const int nt  = j - jm * 6;
    const int m0 = mt * 128;
    const int n0 = nt * 128;

    int e = idx[mt >> 3];                       // 8 m-tiles per batch elem
    e = e < 0 ? 0 : (e > NEXP - 1 ? NEXP - 1 : e);
    const bf16* Bt = Wcat + (size_t)e * HIDDEN * HID_F;
    const int srow   = lane >> 2;
    const int schunk = (((lane & 3) ^ ((lane >> 3) & 3))) * 8;
    const int rchunk = ((lk8 ^ ((lrow >> 1) & 3))) * 8;

    const bf16* gA0 = H  + (size_t)(m0 + wave * 32 + srow) * HID_F + schunk;
    const bf16* gA1 = gA0 + 16 * HID_F;
    const bf16* gB0 = Bt + (size_t)(n0 + wave * 32 + srow) * HID_F + schunk;
    const bf16* gB1 = gB0 + 16 * HID_F;
    bf16* lA0 = As + (wave * 32) * 32;
    bf16* lA1 = lA0 + 16 * 32;
    bf16* lB0 = Bs + (wave * 32) * 32;
    bf16* lB1 = lB0 + 16 * 32;

    f32x4 acc[4][4] = {};
    for (int k0 = 0; k0 < HID_F; k0 += 32) {
        gl2lds16(gA0, lA0); gl2lds16(gA1, lA1);
        gl2lds16(gB0, lB0); gl2lds16(gB1, lB1);
        gA0 += 32; gA1 += 32; gB0 += 32; gB1 += 32;
        __syncthreads();
        bf16x8 af[4], bfr[4];
#pragma unroll
        for (int mi = 0; mi < 4; ++mi)
            af[mi] = *(const bf16x8*)(As + (wm * 64 + mi * 16 + lrow) * 32 + rchunk);
#pragma unroll
        for (int ni = 0; ni < 4; ++ni)
            bfr[ni] = *(const bf16x8*)(Bs + (wn * 64 + ni * 16 + lrow) * 32 + rchunk);
#pragma unroll
        for (int mi = 0; mi < 4; ++mi)
#pragma unroll
            for (int ni = 0; ni < 4; ++ni)
                acc[mi][ni] = __builtin_amdgcn_mfma_f32_16x16x32_bf16(
                    af[mi], bfr[ni], acc[mi][ni], 0, 0, 0);
        __syncthreads();
    }
#pragma unroll
    for (int mi = 0; mi < 4; ++mi) {
#pragma unroll
        for (int ni = 0; ni < 4; ++ni) {
            int col = n0 + wn * 64 + ni * 16 + lrow;
            float bias = (col < SHARED_F) ? b2[col] : be[e * PART + col - SHARED_F];
#pragma unroll
            for (int r = 0; r < 4; ++r) {
                int row = m0 + wm * 64 + mi * 16 + lk8 * 4 + r;
                Out[(size_t)row * HIDDEN + col] = acc[mi][ni][r] + bias;
            }
        }
    }
}

extern "C" void kernel_launch(void* const* d_in, const int* in_sizes, int n_in,
                              void* d_out, int out_size, void* d_ws, size_t ws_size,
                              hipStream_t stream) {
    const float* hidden = (const float*)d_in[0];
    const int*   idx    = (const int*)d_in[1];
    const float* W1     = (const float*)d_in[2];
    const float* b1     = (const float*)d_in[3];
    const float* W2     = (const float*)d_in[4];
    const float* b2     = (const float*)d_in[5];
    const float* We     = (const float*)d_in[6];
    const float* be     = (const float*)d_in[7];
    float* out = (float*)d_out;

    // workspace layout (bytes)
    char* ws = (char*)d_ws;
    bf16* hb   = (bf16*)(ws);                       //  50,331,648 B: [32768][768]
    bf16* h    = (bf16*)(ws + 50331648);            // 201,326,592 B: [32768][3072]
    bf16* W1t  = (bf16*)(ws + 251658240);           //   4,718,592 B: [3072][768]
    bf16* Wcat = (bf16*)(ws + 256376832);           //  28,311,552 B: [6][768][3072]
    // total 284,688,384 B

    // prep
    cvt_f32_bf16<<<4096, 256, 0, stream>>>(
        (const float4*)hidden, (bf16x4*)hb, (M_TOK * HIDDEN) / 4);
    transpose_cvt<<<dim3(HID_F / 32, HIDDEN / 32), 256, 0, stream>>>(
        W1, W1t, HIDDEN, HID_F);
    build_wcat<<<dim3(HIDDEN / 32, HID_F / 32, NEXP), 256, 0, stream>>>(
        W2, We, Wcat);

    // GEMM 1: [32768,768] x [768,3072] -> h (bf16, gelu fused), XCD-swizzled
    fc1_gelu<<<(HID_F / 128) * (M_TOK / 128), 256, 0, stream>>>(hb, W1t, b1, h);

    // GEMM 2: [32768,3072] x [3072,768] -> out (fp32, bias fused), XCD-swizzled
    fc2_moe<<<(HIDDEN / 128) * (M_TOK / 128), 256, 0, stream>>>(
        h, Wcat, b2, be, idx, out);
}